// Round 3
// 1088.445 us; speedup vs baseline: 1.3544x; 1.3544x over previous
//
#include <hip/hip_runtime.h>

// Problem constants (from reference)
#define NU 200000
#define NI 100000
#define DIM 64
#define NE 3200000
#define NT (NU + NI)                     // concatenated destination count
#define CHUNK 2048                       // elements per scan block (256 thr x 8)
#define NB ((NT + CHUNK - 1) / CHUNK)    // 147 scan blocks

static_assert(NB <= 256, "scan2 assumes block sums fit one 256-thread block");

// Established (R0-R8):
//  - ALL float inputs f32; edges int32, dict order. Output is F32, users then items.
//  - Edge-order detector (flag[3]) validated in R7.
// R9-R11: counting-sort -> CSR -> gather SpMM. No fp atomics; each output row
//  written exactly once (degree-0 rows write 0, covering the 0xAA poison).
//  R10/R11 = resubmits: both prior benches died in container acquisition
//  ("container failed twice", no pytest output / no counters — infra, not
//  kernel). Two full device-side audits found no OOB/sync hazards. If this
//  also fails, next round submits the R8 baseline as an infra control.

__device__ __forceinline__ int iclamp(int x, int lo, int hi) {
    return x < lo ? lo : (x > hi ? hi : x);
}

__global__ void zero_i32_kernel(int* __restrict__ p, long long n) {
    long long i = (long long)blockIdx.x * blockDim.x + threadIdx.x;
    long long stride = (long long)gridDim.x * blockDim.x;
    for (; i < n; i += stride) p[i] = 0;
}

__global__ void zero_f32_kernel(float* __restrict__ p, long long n) {
    long long i = (long long)blockIdx.x * blockDim.x + threadIdx.x;
    long long stride = (long long)gridDim.x * blockDim.x;
    for (; i < n; i += stride) p[i] = 0.0f;
}

// flag: [3]=edge_swap  [10]=maxA [11]=maxB  (validated in R7)
__global__ void edge_detect_kernel(const int* __restrict__ a, const int* __restrict__ b,
                                   int n, int* __restrict__ flag) {
    int i = blockIdx.x * blockDim.x + threadIdx.x;
    int stride = gridDim.x * blockDim.x;
    int ma = 0, mb = 0;
    for (; i < n; i += stride) {
        ma = max(ma, a[i]);
        mb = max(mb, b[i]);
    }
    #pragma unroll
    for (int d = 32; d > 0; d >>= 1) {
        ma = max(ma, __shfl_down(ma, d, 64));
        mb = max(mb, __shfl_down(mb, d, 64));
    }
    if ((threadIdx.x & 63) == 0) {
        atomicMax(&flag[10], ma);
        atomicMax(&flag[11], mb);
    }
}
__global__ void finalize_kernel(int* __restrict__ flag) {
    if (threadIdx.x == 0 && blockIdx.x == 0) {
        int ma = flag[10], mb = flag[11];
        flag[3] = (mb >= NI && ma < NI) ? 1 : 0;
    }
}

// ---------------------------------------------------------------------------
// CSR build: histogram over concatenated destinations (users [0,NU), items
// [NU,NT)). Int atomics are small packets (~26 MB total), cheap.
// ---------------------------------------------------------------------------
__global__ __launch_bounds__(256) void hist_kernel(
        const int* __restrict__ a, const int* __restrict__ b,
        const int* __restrict__ flag, int* __restrict__ cnt) {
    int sw = flag[3];
    const int* eu = sw ? b : a;
    const int* ei = sw ? a : b;
    int e = blockIdx.x * blockDim.x + threadIdx.x;
    int stride = gridDim.x * blockDim.x;
    for (; e < NE; e += stride) {
        int u = iclamp(eu[e], 0, NU - 1);
        int i = iclamp(ei[e], 0, NI - 1);
        atomicAdd(&cnt[u], 1);
        atomicAdd(&cnt[NU + i], 1);
    }
}

// Two-level exclusive scan over cnt[0..NT). Because the user region sums to
// exactly NE, rowptr[u] in [0,NE) and rowptr[NU+i] in [NE,2NE) index one
// combined sorted edge-slot space of size 2*NE.
__global__ __launch_bounds__(256) void scan1_kernel(const int* __restrict__ cnt,
                                                    int* __restrict__ bsum) {
    int b = blockIdx.x, t = threadIdx.x;
    int base = b * CHUNK;
    int sum = 0;
    #pragma unroll
    for (int k = 0; k < 8; ++k) {
        int idx = base + k * 256 + t;
        if (idx < NT) sum += cnt[idx];
    }
    #pragma unroll
    for (int d = 32; d > 0; d >>= 1) sum += __shfl_down(sum, d, 64);
    __shared__ int wsum[4];
    if ((t & 63) == 0) wsum[t >> 6] = sum;
    __syncthreads();
    if (t == 0) bsum[b] = wsum[0] + wsum[1] + wsum[2] + wsum[3];
}

__global__ __launch_bounds__(256) void scan2_kernel(int* __restrict__ bsum) {
    __shared__ int sh[256];
    int t = threadIdx.x;
    sh[t] = (t < NB) ? bsum[t] : 0;
    __syncthreads();
    for (int off = 1; off < 256; off <<= 1) {
        int v = (t >= off) ? sh[t - off] : 0;
        __syncthreads();
        sh[t] += v;
        __syncthreads();
    }
    if (t < NB) bsum[t] = (t == 0) ? 0 : sh[t - 1];   // exclusive
}

__global__ __launch_bounds__(256) void scan3_kernel(const int* __restrict__ cnt,
                                                    const int* __restrict__ bsum,
                                                    int* __restrict__ rowptr,
                                                    int* __restrict__ cursor) {
    int b = blockIdx.x, t = threadIdx.x;
    int base = b * CHUNK + t * 8;     // 8 contiguous elements per thread
    int v[8];
    int s = 0;
    #pragma unroll
    for (int k = 0; k < 8; ++k) {
        int idx = base + k;
        v[k] = (idx < NT) ? cnt[idx] : 0;
        s += v[k];
    }
    __shared__ int sh[256];
    sh[t] = s;
    __syncthreads();
    for (int off = 1; off < 256; off <<= 1) {
        int x = (t >= off) ? sh[t - off] : 0;
        __syncthreads();
        sh[t] += x;
        __syncthreads();
    }
    int run = (t == 0 ? 0 : sh[t - 1]) + bsum[b];
    #pragma unroll
    for (int k = 0; k < 8; ++k) {
        int idx = base + k;
        if (idx < NT) {
            rowptr[idx] = run;
            cursor[idx] = run;
            run += v[k];
        }
        if (idx == NT - 1) rowptr[NT] = run;   // == 2*NE
    }
}

// Scatter edges into sorted slots. Every slot in colS/valS[0..2*NE) is written
// exactly once, so no pre-zero of those arrays is needed.
__global__ __launch_bounds__(256) void scatter_kernel(
        const int* __restrict__ a, const int* __restrict__ b,
        const int* __restrict__ flag, const float* __restrict__ ev,
        int* __restrict__ cursor, int* __restrict__ colS, float* __restrict__ valS) {
    int sw = flag[3];
    const int* eu = sw ? b : a;
    const int* ei = sw ? a : b;
    int e = blockIdx.x * blockDim.x + threadIdx.x;
    int stride = gridDim.x * blockDim.x;
    for (; e < NE; e += stride) {
        int u = iclamp(eu[e], 0, NU - 1);
        int i = iclamp(ei[e], 0, NI - 1);
        float v = ev[e];
        int p0 = atomicAdd(&cursor[u], 1);       // user slot: stores item idx
        colS[p0] = i; valS[p0] = v;
        int p1 = atomicAdd(&cursor[NU + i], 1);  // item slot: stores user idx
        colS[p1] = u; valS[p1] = v;
    }
}

// ---------------------------------------------------------------------------
// Gather SpMM: one wave per output row, lane = dim. Sequential (col,val)
// reads; 256 B coalesced embedding-row gathers; one coalesced row store.
// Degree-0 rows write 0 (covers the 0xAA-poisoned output, no zero pass).
// ---------------------------------------------------------------------------
__global__ __launch_bounds__(256) void spmm_kernel(
        const int* __restrict__ rowptr, const int* __restrict__ colS,
        const float* __restrict__ valS, const float* __restrict__ emb,
        float* __restrict__ outp, int nrows, int row_off) {
    int gw = (int)(((long long)blockIdx.x * blockDim.x + threadIdx.x) >> 6);
    int lane = threadIdx.x & 63;
    if (gw >= nrows) return;
    int s = rowptr[row_off + gw];
    int e = rowptr[row_off + gw + 1];
    float acc0 = 0.0f, acc1 = 0.0f, acc2 = 0.0f, acc3 = 0.0f;
    int k = s;
    for (; k + 4 <= e; k += 4) {
        int c0 = colS[k];     float v0 = valS[k];
        int c1 = colS[k + 1]; float v1 = valS[k + 1];
        int c2 = colS[k + 2]; float v2 = valS[k + 2];
        int c3 = colS[k + 3]; float v3 = valS[k + 3];
        acc0 += v0 * emb[(size_t)c0 * DIM + lane];
        acc1 += v1 * emb[(size_t)c1 * DIM + lane];
        acc2 += v2 * emb[(size_t)c2 * DIM + lane];
        acc3 += v3 * emb[(size_t)c3 * DIM + lane];
    }
    for (; k < e; ++k) {
        int c = colS[k]; float v = valS[k];
        acc0 += v * emb[(size_t)c * DIM + lane];
    }
    outp[(size_t)gw * DIM + lane] = (acc0 + acc1) + (acc2 + acc3);
}

// ---------------------------------------------------------------------------
// Fallback (R8 path): direct fp-atomic accumulate — used only if ws too small.
// ---------------------------------------------------------------------------
__global__ __launch_bounds__(256) void edge_atomic_kernel(
        const int* __restrict__ a, const int* __restrict__ b,
        const int* __restrict__ flag,
        const float* __restrict__ ev,
        const float* __restrict__ uemb, const float* __restrict__ iemb,
        float* __restrict__ outU, float* __restrict__ outI) {
    int sw = flag[3];
    const int* eu = sw ? b : a;
    const int* ei = sw ? a : b;
    long long t = (long long)blockIdx.x * blockDim.x + threadIdx.x;
    int lane = (int)(t & 63);
    long long e = t >> 6;
    if (e >= NE) return;
    int u = iclamp(eu[e], 0, NU - 1);
    int i = iclamp(ei[e], 0, NI - 1);
    float v  = ev[e];
    float xu = uemb[(size_t)u * DIM + lane];
    float xi = iemb[(size_t)i * DIM + lane];
    atomicAdd(&outU[(size_t)u * DIM + lane], v * xi);
    atomicAdd(&outI[(size_t)i * DIM + lane], v * xu);
}

// ===========================================================================
extern "C" void kernel_launch(void* const* d_in, const int* in_sizes, int n_in,
                              void* d_out, int out_size, void* d_ws, size_t ws_size,
                              hipStream_t stream) {
    // Identify embedding slots by element count (insurance against slot swap).
    const float* user_emb = (const float*)d_in[0];
    const float* item_emb = (const float*)d_in[1];
    if (in_sizes[0] == NI * DIM && in_sizes[1] == NU * DIM) {
        user_emb = (const float*)d_in[1];
        item_emb = (const float*)d_in[0];
    }
    const int*   edge_a   = (const int*)d_in[2];
    const int*   edge_b   = (const int*)d_in[3];
    const float* edge_val = (const float*)d_in[4];

    float* out = (float*)d_out;                 // F32 output
    float* out_users = out;                     // users first
    float* out_items = out + (size_t)NU * DIM;

    const long long NOUT = (long long)(NU + NI) * DIM;   // 19.2M f32

    // Workspace layout (4 B units):
    //  flag[16] | cnt[NT] | rowptr[NT+1] | cursor[NT] | bsum[256] |
    //  colS[2*NE] | valS[2*NE]
    int* flag = (int*)d_ws;
    const size_t need_units = (size_t)16 + NT + (NT + 1) + NT + 256
                            + (size_t)2 * NE + (size_t)2 * NE;
    const size_t need_bytes = need_units * 4;

    if (ws_size >= need_bytes) {
        int*   cnt    = flag + 16;
        int*   rowptr = cnt + NT;
        int*   cursor = rowptr + NT + 1;
        int*   bsum   = cursor + NT;
        int*   colS   = bsum + 256;
        float* valS   = (float*)(colS + (size_t)2 * NE);

        // flag + cnt must start at zero every launch.
        zero_i32_kernel<<<1024, 256, 0, stream>>>(flag, 16 + (long long)NT);
        edge_detect_kernel<<<512, 256, 0, stream>>>(edge_a, edge_b, NE, flag);
        finalize_kernel<<<1, 64, 0, stream>>>(flag);
        hist_kernel<<<3200, 256, 0, stream>>>(edge_a, edge_b, flag, cnt);
        scan1_kernel<<<NB, 256, 0, stream>>>(cnt, bsum);
        scan2_kernel<<<1, 256, 0, stream>>>(bsum);
        scan3_kernel<<<NB, 256, 0, stream>>>(cnt, bsum, rowptr, cursor);
        scatter_kernel<<<3200, 256, 0, stream>>>(edge_a, edge_b, flag, edge_val,
                                                 cursor, colS, valS);
        // users: gather item rows; items: gather user rows.
        spmm_kernel<<<(NU * 64 + 255) / 256, 256, 0, stream>>>(
            rowptr, colS, valS, item_emb, out_users, NU, 0);
        spmm_kernel<<<(NI * 64 + 255) / 256, 256, 0, stream>>>(
            rowptr, colS, valS, user_emb, out_items, NI, NU);
    } else {
        // Fallback: proven R8 atomic path.
        zero_i32_kernel<<<1, 64, 0, stream>>>(flag, 16);
        edge_detect_kernel<<<512, 256, 0, stream>>>(edge_a, edge_b, NE, flag);
        finalize_kernel<<<1, 64, 0, stream>>>(flag);
        zero_f32_kernel<<<2048, 256, 0, stream>>>(out, NOUT);
        long long nthreads = (long long)NE * 64;
        edge_atomic_kernel<<<(int)(nthreads / 256), 256, 0, stream>>>(
            edge_a, edge_b, flag, edge_val, user_emb, item_emb, out_users, out_items);
    }
}